// Round 12
// baseline (99.139 us; speedup 1.0000x reference)
//
#include <hip/hip_runtime.h>

#define NQ 32768
#define NP 8192
#define FD 32
#define KNN 8
#define QW 8                 // queries per wave
#define WPB 4                // waves per block
#define TB 256
#define QBLK (QW * WPB)      // 32 queries per block
#define CHP 1024             // points per staged chunk
#define NCH (NP / CHP)       // 8
#define ABLK 2048            // phase-A points (global stream, min-only)
#define CAP 128              // candidate capacity (E~40, P(overflow)~1e-7/query)

typedef unsigned long long u64;

__device__ __forceinline__ u64 shfl_xor_u64(u64 k, int j) {
    unsigned lo = __shfl_xor((unsigned)k, j);
    unsigned hi = __shfl_xor((unsigned)(k >> 32), j);
    return ((u64)hi << 32) | lo;
}
// full 64-lane bitonic sort, ascending by lane (r5-verified pattern)
__device__ __forceinline__ u64 sort64_u64(u64 key, int lane) {
    for (int k2 = 2; k2 <= 64; k2 <<= 1)
        for (int j = k2 >> 1; j > 0; j >>= 1) {
            u64 o = shfl_xor_u64(key, j);
            bool keepMin = ((lane & k2) == 0) == ((lane & j) == 0);
            key = ((o < key) == keepMin) ? o : key;
        }
    return key;
}
// exact 8th-smallest of the 64 lane values (r6-verified f32 bitonic + readlane 7)
__device__ __forceinline__ float eighth_smallest64(float v, int lane) {
    for (int k2 = 2; k2 <= 64; k2 <<= 1)
        for (int j = k2 >> 1; j > 0; j >>= 1) {
            float o = __shfl_xor(v, j);
            bool keepMin = ((lane & k2) == 0) == ((lane & j) == 0);
            v = ((o < v) == keepMin) ? o : v;
        }
    return __uint_as_float((unsigned)__builtin_amdgcn_readlane((int)__float_as_uint(v), 7));
}

// prepack: pts4[i] = (-2x, -2y, -2z, pn_screen) — screen-space only (Phase C re-derives
// np-exact values from the original points array)
__global__ void k_prepack(const float* __restrict__ points, float4* __restrict__ pts4) {
    int i = blockIdx.x * blockDim.x + threadIdx.x;   // grid exactly NP
    float px = points[i * 3 + 0], py = points[i * 3 + 1], pz = points[i * 3 + 2];
    float pn = __builtin_fmaf(pz, pz, __builtin_fmaf(py, py, px * px));
    pts4[i] = make_float4(-2.0f * px, -2.0f * py, -2.0f * pz, pn);
}

__global__ __launch_bounds__(TB) void knn_kernel(
    const float* __restrict__ xyz, const float* __restrict__ points,
    const float* __restrict__ feats, const float4* __restrict__ pts4,
    float* __restrict__ out)
{
#pragma clang fp contract(off)   // np-exact paths: explicit mul/add; fast paths: explicit fmaf
    __shared__ float4 sp[CHP];                    // 16 KB staged chunk (pure copy of pts4)
    __shared__ unsigned short sidx16[QBLK * CAP]; // 8 KB candidate indices
    __shared__ int scnt[QBLK];

    const int t     = threadIdx.x;
    const int lane  = t & 63;
    const int wid   = t >> 6;
    const int qbase = blockIdx.x * QBLK + wid * QW;

    if (t < QBLK) scnt[t] = 0;

    float qx[QW], qy[QW], qz[QW], qn[QW], mn[QW], tscr[QW];
#pragma unroll
    for (int qq = 0; qq < QW; ++qq) {
        int q = qbase + qq;
        float a = xyz[q * 3 + 0], b = xyz[q * 3 + 1], c = xyz[q * 3 + 2];
        qx[qq] = a; qy[qq] = b; qz[qq] = c;
        qn[qq] = (a * a + b * b) + c * c;   // np-exact: rounded squares, sequential add
        mn[qq] = __builtin_inff();
    }

    // ---- Phase A: global min-only stream over pts4[0..ABLK) (no LDS, no barriers) ----
#pragma unroll 4
    for (int s = 0; s < ABLK / 64; ++s) {
        float4 p = pts4[s * 64 + lane];
#pragma unroll
        for (int qq = 0; qq < QW; ++qq) {
            float g = __builtin_fmaf(qx[qq], p.x,
                      __builtin_fmaf(qy[qq], p.y,
                      __builtin_fmaf(qz[qq], p.z, p.w)));
            mn[qq] = fminf(mn[qq], g);
        }
    }
    // tight valid bound: 8th-smallest of 64 lane-mins (disjoint point subsets =>
    // >= 8 distinct actual g-values <= tau => upper-bounds full-set 8th smallest)
#pragma unroll
    for (int qq = 0; qq < QW; ++qq)
        tscr[qq] = eighth_smallest64(mn[qq], lane) + 1e-3f;  // margin >> g-vs-np-d2 gap

    // ---- Phase B: screen all NP points from LDS-staged chunks ----
    for (int c = 0; c < NCH; ++c) {
        __syncthreads();
        for (int i = t; i < CHP; i += TB) sp[i] = pts4[c * CHP + i];   // pure 16B copy
        __syncthreads();
#pragma unroll 4
        for (int s = 0; s < CHP / 64; ++s) {
            float4 p = sp[s * 64 + lane];
#pragma unroll
            for (int qq = 0; qq < QW; ++qq) {
                float g = __builtin_fmaf(qx[qq], p.x,
                          __builtin_fmaf(qy[qq], p.y,
                          __builtin_fmaf(qz[qq], p.z, p.w)));
                if (__builtin_expect(g <= tscr[qq], 0)) {
                    int wq = wid * QW + qq;
                    int slot = atomicAdd(&scnt[wq], 1);
                    if (slot < CAP) sidx16[wq * CAP + slot] = (unsigned short)(c * CHP + s * 64 + lane);
                }
            }
        }
    }
    __syncthreads();
    // each wave owns its queries' candidate lists from here

    // ---- Phase C: np-exact d2 recompute, u64 sort(s), top-8, output (r10/r11-verified) ----
    const float4* feats4 = (const float4*)feats;
    float4* outf4 = (float4*)(out + (long)NQ * KNN * 3);
#pragma unroll 1
    for (int qq = 0; qq < QW; ++qq) {
        int wq = wid * QW + qq;
        int cnt = scnt[wq]; if (cnt > CAP) cnt = CAP;

        u64 key1 = ~0ull;
        if (lane < cnt) {
            int idx = sidx16[wq * CAP + lane];
            float px = points[idx * 3 + 0], py = points[idx * 3 + 1], pz = points[idx * 3 + 2];
            float pn  = (px * px + py * py) + pz * pz;                 // np-exact
            float dot = __builtin_fmaf(qz[qq], pz, __builtin_fmaf(qy[qq], py, qx[qq] * px));
            float d2  = (qn[qq] - 2.0f * dot) + pn;
            unsigned b = __float_as_uint(d2);
            unsigned mk = (b & 0x80000000u) ? ~b : (b | 0x80000000u);  // monotone map
            key1 = ((u64)mk << 32) | (unsigned)idx;                    // (value, stable idx)
        }
        u64 v = sort64_u64(key1, lane);

        if (cnt > 64) {                       // wave-uniform, ~1% of queries
            u64 key2 = ~0ull;
            if (lane + 64 < cnt) {
                int idx = sidx16[wq * CAP + 64 + lane];
                float px = points[idx * 3 + 0], py = points[idx * 3 + 1], pz = points[idx * 3 + 2];
                float pn  = (px * px + py * py) + pz * pz;
                float dot = __builtin_fmaf(qz[qq], pz, __builtin_fmaf(qy[qq], py, qx[qq] * px));
                float d2  = (qn[qq] - 2.0f * dot) + pn;
                unsigned b = __float_as_uint(d2);
                unsigned mk = (b & 0x80000000u) ? ~b : (b | 0x80000000u);
                key2 = ((u64)mk << 32) | (unsigned)idx;
            }
            u64 s2 = sort64_u64(key2, lane);
            // lanes 8..15 take s2[15-lane] (descending) -> lanes 0..15 bitonic; 4-step merge
            int src = (15 - lane) & 63;
            unsigned lo2 = __shfl((unsigned)s2, src);
            unsigned hi2 = __shfl((unsigned)(s2 >> 32), src);
            u64 kr = ((u64)hi2 << 32) | lo2;
            u64 m = (lane < 8) ? v : ((lane < 16) ? kr : ~0ull);
#pragma unroll
            for (int j = 8; j > 0; j >>= 1) {
                u64 o = shfl_xor_u64(m, j);
                bool low = (lane & j) == 0;
                m = low ? (o < m ? o : m) : (o < m ? m : o);
            }
            v = m;
        }

        // lanes 0..7 hold top-8 ascending (r5/r6-verified output layout)
        int q = qbase + qq;
        int nb = __shfl((int)(unsigned)v, lane >> 3);
        outf4[(long)q * (KNN * FD / 4) + lane] = feats4[(long)nb * (FD / 4) + (lane & 7)];
        int j2 = lane / 3;
        int nb2 = __shfl((int)(unsigned)v, j2);
        if (lane < 24) {
            out[(long)q * (KNN * 3) + lane] = points[nb2 * 3 + (lane - j2 * 3)];
        }
    }
}

extern "C" void kernel_launch(void* const* d_in, const int* in_sizes, int n_in,
                              void* d_out, int out_size, void* d_ws, size_t ws_size,
                              hipStream_t stream) {
    const float* xyz    = (const float*)d_in[0];
    const float* points = (const float*)d_in[1];
    const float* feats  = (const float*)d_in[2];
    float* out = (float*)d_out;
    float4* pts4 = (float4*)d_ws;   // 128 KB scratch

    hipLaunchKernelGGL(k_prepack, dim3(NP / 256), dim3(256), 0, stream, points, pts4);
    hipLaunchKernelGGL(knn_kernel, dim3(NQ / QBLK), dim3(TB), 0, stream,
                       xyz, points, feats, pts4, out);
}

// Round 13
// 77.426 us; speedup vs baseline: 1.2804x; 1.2804x over previous
//
#include <hip/hip_runtime.h>

#define NQ 32768
#define NP 8192
#define FD 32
#define KNN 8
#define QW 4                 // queries per wave
#define WPB 8                // waves per block
#define TB 512
#define QBLK (QW * WPB)      // 32 queries per block
#define CHP 1024             // points per staged chunk
#define NCH (NP / CHP)       // 8
#define ABLK 2048            // phase-A points (global stream, min-only)
#define CAP 128              // candidate capacity (E~32, r12-validated)

typedef unsigned long long u64;

__device__ __forceinline__ u64 shfl_xor_u64(u64 k, int j) {
    unsigned lo = __shfl_xor((unsigned)k, j);
    unsigned hi = __shfl_xor((unsigned)(k >> 32), j);
    return ((u64)hi << 32) | lo;
}
// full 64-lane bitonic sort, ascending by lane (r5-verified pattern)
__device__ __forceinline__ u64 sort64_u64(u64 key, int lane) {
    for (int k2 = 2; k2 <= 64; k2 <<= 1)
        for (int j = k2 >> 1; j > 0; j >>= 1) {
            u64 o = shfl_xor_u64(key, j);
            bool keepMin = ((lane & k2) == 0) == ((lane & j) == 0);
            key = ((o < key) == keepMin) ? o : key;
        }
    return key;
}
// exact 8th-smallest of the 64 lane values (r6-verified f32 bitonic + readlane 7)
__device__ __forceinline__ float eighth_smallest64(float v, int lane) {
    for (int k2 = 2; k2 <= 64; k2 <<= 1)
        for (int j = k2 >> 1; j > 0; j >>= 1) {
            float o = __shfl_xor(v, j);
            bool keepMin = ((lane & k2) == 0) == ((lane & j) == 0);
            v = ((o < v) == keepMin) ? o : v;
        }
    return __uint_as_float((unsigned)__builtin_amdgcn_readlane((int)__float_as_uint(v), 7));
}

// prepack: pts4[i] = (-2x, -2y, -2z, pn_screen) — screen-space only (Phase C re-derives
// np-exact values from the original points array)
__global__ void k_prepack(const float* __restrict__ points, float4* __restrict__ pts4) {
    int i = blockIdx.x * blockDim.x + threadIdx.x;   // grid exactly NP
    float px = points[i * 3 + 0], py = points[i * 3 + 1], pz = points[i * 3 + 2];
    float pn = __builtin_fmaf(pz, pz, __builtin_fmaf(py, py, px * px));
    pts4[i] = make_float4(-2.0f * px, -2.0f * py, -2.0f * pz, pn);
}

__global__ __launch_bounds__(TB) void knn_kernel(
    const float* __restrict__ xyz, const float* __restrict__ points,
    const float* __restrict__ feats, const float4* __restrict__ pts4,
    float* __restrict__ out)
{
#pragma clang fp contract(off)   // np-exact paths: explicit mul/add; fast paths: explicit fmaf
    __shared__ float4 sp[CHP];                    // 16 KB staged chunk (pure copy of pts4)
    __shared__ unsigned short sidx16[QBLK * CAP]; // 8 KB candidate indices
    __shared__ int scnt[QBLK];

    const int t     = threadIdx.x;
    const int lane  = t & 63;
    const int wid   = t >> 6;
    const int qbase = blockIdx.x * QBLK + wid * QW;

    if (t < QBLK) scnt[t] = 0;

    float qx[QW], qy[QW], qz[QW], qn[QW], mn[QW], tscr[QW];
#pragma unroll
    for (int qq = 0; qq < QW; ++qq) {
        int q = qbase + qq;
        float a = xyz[q * 3 + 0], b = xyz[q * 3 + 1], c = xyz[q * 3 + 2];
        qx[qq] = a; qy[qq] = b; qz[qq] = c;
        qn[qq] = (a * a + b * b) + c * c;   // np-exact: rounded squares, sequential add
        mn[qq] = __builtin_inff();
    }

    // ---- Phase A: global min-only stream over pts4[0..ABLK) (no LDS, no barriers;
    //      8 waves/block + 4 blocks/CU hide the L2 latency) ----
#pragma unroll 4
    for (int s = 0; s < ABLK / 64; ++s) {
        float4 p = pts4[s * 64 + lane];
#pragma unroll
        for (int qq = 0; qq < QW; ++qq) {
            float g = __builtin_fmaf(qx[qq], p.x,
                      __builtin_fmaf(qy[qq], p.y,
                      __builtin_fmaf(qz[qq], p.z, p.w)));
            mn[qq] = fminf(mn[qq], g);
        }
    }
    // tight valid bound: 8th-smallest of 64 lane-mins (disjoint point subsets =>
    // 8 distinct actual g-values <= tau => upper-bounds full-set 8th smallest)
#pragma unroll
    for (int qq = 0; qq < QW; ++qq)
        tscr[qq] = eighth_smallest64(mn[qq], lane) + 1e-3f;  // margin >> g-vs-np-d2 gap

    // ---- Phase B: screen all NP points from LDS-staged chunks (pure copy staging) ----
    for (int c = 0; c < NCH; ++c) {
        __syncthreads();
        for (int i = t; i < CHP; i += TB) sp[i] = pts4[c * CHP + i];   // 16B copy
        __syncthreads();
#pragma unroll 4
        for (int s = 0; s < CHP / 64; ++s) {
            float4 p = sp[s * 64 + lane];
#pragma unroll
            for (int qq = 0; qq < QW; ++qq) {
                float g = __builtin_fmaf(qx[qq], p.x,
                          __builtin_fmaf(qy[qq], p.y,
                          __builtin_fmaf(qz[qq], p.z, p.w)));
                if (__builtin_expect(g <= tscr[qq], 0)) {
                    int wq = wid * QW + qq;
                    int slot = atomicAdd(&scnt[wq], 1);
                    if (slot < CAP) sidx16[wq * CAP + slot] = (unsigned short)(c * CHP + s * 64 + lane);
                }
            }
        }
    }
    __syncthreads();
    // each wave owns its queries' candidate lists from here

    // ---- Phase C: np-exact d2 recompute, u64 sort(s), top-8, output (r10-12-verified) ----
    const float4* feats4 = (const float4*)feats;
    float4* outf4 = (float4*)(out + (long)NQ * KNN * 3);
#pragma unroll 1
    for (int qq = 0; qq < QW; ++qq) {
        int wq = wid * QW + qq;
        int cnt = scnt[wq]; if (cnt > CAP) cnt = CAP;

        u64 key1 = ~0ull;
        if (lane < cnt) {
            int idx = sidx16[wq * CAP + lane];
            float px = points[idx * 3 + 0], py = points[idx * 3 + 1], pz = points[idx * 3 + 2];
            float pn  = (px * px + py * py) + pz * pz;                 // np-exact
            float dot = __builtin_fmaf(qz[qq], pz, __builtin_fmaf(qy[qq], py, qx[qq] * px));
            float d2  = (qn[qq] - 2.0f * dot) + pn;
            unsigned b = __float_as_uint(d2);
            unsigned mk = (b & 0x80000000u) ? ~b : (b | 0x80000000u);  // monotone map
            key1 = ((u64)mk << 32) | (unsigned)idx;                    // (value, stable idx)
        }
        u64 v = sort64_u64(key1, lane);

        if (cnt > 64) {                       // wave-uniform, rare (mean cnt ~32)
            u64 key2 = ~0ull;
            if (lane + 64 < cnt) {
                int idx = sidx16[wq * CAP + 64 + lane];
                float px = points[idx * 3 + 0], py = points[idx * 3 + 1], pz = points[idx * 3 + 2];
                float pn  = (px * px + py * py) + pz * pz;
                float dot = __builtin_fmaf(qz[qq], pz, __builtin_fmaf(qy[qq], py, qx[qq] * px));
                float d2  = (qn[qq] - 2.0f * dot) + pn;
                unsigned b = __float_as_uint(d2);
                unsigned mk = (b & 0x80000000u) ? ~b : (b | 0x80000000u);
                key2 = ((u64)mk << 32) | (unsigned)idx;
            }
            u64 s2 = sort64_u64(key2, lane);
            // lanes 8..15 take s2[15-lane] (descending) -> lanes 0..15 bitonic; 4-step merge
            int src = (15 - lane) & 63;
            unsigned lo2 = __shfl((unsigned)s2, src);
            unsigned hi2 = __shfl((unsigned)(s2 >> 32), src);
            u64 kr = ((u64)hi2 << 32) | lo2;
            u64 m = (lane < 8) ? v : ((lane < 16) ? kr : ~0ull);
#pragma unroll
            for (int j = 8; j > 0; j >>= 1) {
                u64 o = shfl_xor_u64(m, j);
                bool low = (lane & j) == 0;
                m = low ? (o < m ? o : m) : (o < m ? m : o);
            }
            v = m;
        }

        // lanes 0..7 hold top-8 ascending (r5/r6-verified output layout)
        int q = qbase + qq;
        int nb = __shfl((int)(unsigned)v, lane >> 3);
        outf4[(long)q * (KNN * FD / 4) + lane] = feats4[(long)nb * (FD / 4) + (lane & 7)];
        int j2 = lane / 3;
        int nb2 = __shfl((int)(unsigned)v, j2);
        if (lane < 24) {
            out[(long)q * (KNN * 3) + lane] = points[nb2 * 3 + (lane - j2 * 3)];
        }
    }
}

extern "C" void kernel_launch(void* const* d_in, const int* in_sizes, int n_in,
                              void* d_out, int out_size, void* d_ws, size_t ws_size,
                              hipStream_t stream) {
    const float* xyz    = (const float*)d_in[0];
    const float* points = (const float*)d_in[1];
    const float* feats  = (const float*)d_in[2];
    float* out = (float*)d_out;
    float4* pts4 = (float4*)d_ws;   // 128 KB scratch

    hipLaunchKernelGGL(k_prepack, dim3(NP / 256), dim3(256), 0, stream, points, pts4);
    hipLaunchKernelGGL(knn_kernel, dim3(NQ / QBLK), dim3(TB), 0, stream,
                       xyz, points, feats, pts4, out);
}